// Round 3
// baseline (240.455 us; speedup 1.0000x reference)
//
#include <hip/hip_runtime.h>
#include <stdint.h>

#define NG 256      // num networks
#define KF 256      // IN_F
#define OF 256      // OUT_F
#define BM 128      // rows per tile
#define BK 32       // k-chunk
#define NKT 8       // KF / BK
#define NTILES 16   // PAD / BM
#define NTH 512     // 8 waves

using f32x4  = __attribute__((ext_vector_type(4))) float;
using bf16x8 = __attribute__((ext_vector_type(8))) __bf16;
using u16x8  = __attribute__((ext_vector_type(8))) unsigned short;

__device__ __forceinline__ unsigned short f2bf(float f) {
  unsigned u = __builtin_bit_cast(unsigned, f);
  u += 0x7fffu + ((u >> 16) & 1u);   // round-to-nearest-even
  return (unsigned short)(u >> 16);
}

// ---------------- offsets scan (1 block, 256 threads) ----------------
__global__ void scan_kernel(const int* __restrict__ counts, int* __restrict__ offs) {
  __shared__ int s[NG];
  int t = threadIdx.x;
  s[t] = counts[t];
  __syncthreads();
  #pragma unroll
  for (int d = 1; d < NG; d <<= 1) {
    int u = (t >= d) ? s[t - d] : 0;
    __syncthreads();
    s[t] += u;
    __syncthreads();
  }
  if (t == 0) offs[0] = 0;
  offs[t + 1] = s[t];
}

// ---------------- W f32 -> bf16 pre-swizzled image ----------------
// Image slot16 index = ((g*8 + kt)*256 + o)*4 + s  (16B each); holds
// W[g][o][kt*32 + (s ^ (o&3))*8 .. +8] as bf16x8. Linear global_load_lds
// into LDS then byte (o*64 + slot*16) gives the XOR-swizzled layout.
__global__ __launch_bounds__(512)
void wconv_kernel(const float* __restrict__ w, unsigned short* __restrict__ img) {
  int tid = blockIdx.x * 512 + threadIdx.x;   // one 16B slot each, 2^21 total
  int s  = tid & 3;
  int o  = (tid >> 2) & 255;
  int kt = (tid >> 10) & 7;
  int g  = tid >> 13;
  int k0 = kt * 32 + ((s ^ (o & 3)) << 3);
  const float* src = w + ((size_t)(g * 256 + o) * 256 + k0);
  f32x4 a = *(const f32x4*)src;
  f32x4 b = *(const f32x4*)(src + 4);
  u16x8 r;
  r[0]=f2bf(a[0]); r[1]=f2bf(a[1]); r[2]=f2bf(a[2]); r[3]=f2bf(a[3]);
  r[4]=f2bf(b[0]); r[5]=f2bf(b[1]); r[6]=f2bf(b[2]); r[7]=f2bf(b[3]);
  *(u16x8*)(img + (size_t)tid * 8) = r;
}

// ---------------- grouped GEMM ----------------
template<bool PRECONV>
__global__ __launch_bounds__(NTH, 4)
void gemm_kernel(const float* __restrict__ x,
                 const float* __restrict__ wf32,
                 const unsigned short* __restrict__ wimg,
                 const float* __restrict__ bias,
                 const int* __restrict__ offs,
                 float* __restrict__ out)
{
  __shared__ __align__(16) unsigned short Bs[3][OF * BK];  // 3 x 16KB = 48KB

  const int g      = blockIdx.y;
  const int r0     = offs[g];
  const int cnt    = offs[g + 1] - r0;
  const int tstart = blockIdx.x * BM;
  if (tstart >= cnt) return;
  const int mrows = min(BM, cnt - tstart);
  const int row0  = r0 + tstart;

  const int tid  = threadIdx.x;
  const int lane = tid & 63;
  const int w    = tid >> 6;      // wave 0..7, owns rows [w*16, w*16+16)
  const int lrow = lane & 15;
  const int lk   = lane >> 4;     // 0..3

  // A supply row for this lane (clamped: invalid rows only feed unstored cols)
  const int arow = w * 16 + lrow;
  const int ar   = row0 + min(arow, mrows - 1);
  const float* aptr = x + (size_t)ar * KF + lk * 8;

  f32x4 areg[2][2];
  auto issueA = [&](int kt) {
    const float* p = aptr + kt * BK;
    areg[kt & 1][0] = *(const f32x4*)(p);
    areg[kt & 1][1] = *(const f32x4*)(p + 4);
  };
  auto mkfrag = [&](int kt) -> bf16x8 {
    f32x4 lo = areg[kt & 1][0], hi = areg[kt & 1][1];
    u16x8 r;
    r[0]=f2bf(lo[0]); r[1]=f2bf(lo[1]); r[2]=f2bf(lo[2]); r[3]=f2bf(lo[3]);
    r[4]=f2bf(hi[0]); r[5]=f2bf(hi[1]); r[6]=f2bf(hi[2]); r[7]=f2bf(hi[3]);
    return __builtin_bit_cast(bf16x8, r);
  };

  auto issueB = [&](int kt, int buf) {
    const char* sb = (const char*)wimg + ((size_t)g << 17) + (size_t)kt * 16384;
    #pragma unroll
    for (int r = 0; r < 2; ++r) {
      int c = w * 2 + r;                                  // 16 x 1KB chunks
      __builtin_amdgcn_global_load_lds(
          (const __attribute__((address_space(1))) void*)(sb + c * 1024 + lane * 16),
          (__attribute__((address_space(3))) void*)((char*)&Bs[buf][0] + c * 1024),
          16, 0, 0);
    }
  };

  f32x4 acc[16] = {};
  const int slot  = lk ^ (lrow & 3);          // XOR slot swizzle (o&3 == lrow&3)
  const int bbase = lrow * 32 + slot * 8;     // ushort index within o-row

  auto compute = [&](int kt, int buf) {
    bf16x8 af = mkfrag(kt);
    #pragma unroll
    for (int n = 0; n < 16; ++n) {
      bf16x8 wf = *(const bf16x8*)&Bs[buf][n * 512 + bbase];
      // swapped operands: D[o][xrow] -> lane holds 4 consecutive out cols
      acc[n] = __builtin_amdgcn_mfma_f32_16x16x32_bf16(wf, af, acc[n], 0, 0, 0);
    }
  };

  if (PRECONV) {
    // prologue: A(0), B(0), B(1)  (FIFO: A0, B0 complete at vmcnt(2), B1 flies)
    issueA(0);
    issueB(0, 0);
    issueB(1, 1);
    #pragma unroll
    for (int kt = 0; kt < NKT; ++kt) {
      if (kt < NKT - 1) asm volatile("s_waitcnt vmcnt(2)" ::: "memory");
      else              asm volatile("s_waitcnt vmcnt(0)" ::: "memory");
      __builtin_amdgcn_s_barrier();
      __builtin_amdgcn_sched_barrier(0);
      if (kt + 1 < NKT) issueA(kt + 1);
      if (kt + 2 < NKT) issueB(kt + 2, (kt + 2) % 3);
      __builtin_amdgcn_sched_barrier(0);
      compute(kt, kt % 3);
    }
  } else {
    // fallback (ws too small): stage B from f32 weights, simple 2-barrier loop
    #pragma unroll
    for (int kt = 0; kt < NKT; ++kt) {
      u16x8 v[2];
      #pragma unroll
      for (int r = 0; r < 2; ++r) {
        int sl = tid + r * 512;             // 1024 slot16s per kt-image
        int o  = sl >> 2, s = sl & 3;
        int k  = kt * 32 + ((s ^ (o & 3)) << 3);
        const float* src = wf32 + ((size_t)(g * 256 + o) * 256 + k);
        f32x4 a = *(const f32x4*)src;
        f32x4 b = *(const f32x4*)(src + 4);
        v[r][0]=f2bf(a[0]); v[r][1]=f2bf(a[1]); v[r][2]=f2bf(a[2]); v[r][3]=f2bf(a[3]);
        v[r][4]=f2bf(b[0]); v[r][5]=f2bf(b[1]); v[r][6]=f2bf(b[2]); v[r][7]=f2bf(b[3]);
      }
      __syncthreads();   // previous compute done reading Bs[0]
      #pragma unroll
      for (int r = 0; r < 2; ++r) {
        int sl = tid + r * 512;
        *(u16x8*)&Bs[0][sl * 8] = v[r];
      }
      __syncthreads();
      issueA(kt);
      compute(kt, 0);
    }
  }

  // epilogue: f32x4 stores, one wave-level row guard
  if (arow < mrows) {
    float* orow = out + (size_t)(row0 + arow) * OF;
    const float* brow = bias + g * OF;
    #pragma unroll
    for (int n = 0; n < 16; ++n) {
      f32x4 b4 = *(const f32x4*)&brow[n * 16 + lk * 4];
      f32x4 v  = acc[n] + b4;
      *(f32x4*)&orow[n * 16 + lk * 4] = v;
    }
  }
}

extern "C" void kernel_launch(void* const* d_in, const int* in_sizes, int n_in,
                              void* d_out, int out_size, void* d_ws, size_t ws_size,
                              hipStream_t stream) {
  const float* weight = (const float*)d_in[0];
  const float* bias   = (const float*)d_in[1];
  const float* x      = (const float*)d_in[2];
  const int*   counts = (const int*)d_in[3];
  float* out = (float*)d_out;

  int* offs = (int*)d_ws;
  unsigned short* wimg = (unsigned short*)((char*)d_ws + 4096);
  const size_t need = 4096 + (size_t)NG * 8 * 16384;  // ~32 MB image

  scan_kernel<<<1, 256, 0, stream>>>(counts, offs);

  if (ws_size >= need) {
    wconv_kernel<<<(NG * 8 * 256 * 4) / 512, 512, 0, stream>>>(weight, wimg);
    gemm_kernel<true><<<dim3(NTILES, NG), NTH, 0, stream>>>(x, weight, wimg, bias, offs, out);
  } else {
    gemm_kernel<false><<<dim3(NTILES, NG), NTH, 0, stream>>>(x, weight, wimg, bias, offs, out);
  }
}